// Round 2
// baseline (355.090 us; speedup 1.0000x reference)
//
#include <hip/hip_runtime.h>
#include <math.h>

#define NTOK 16384
#define DDIM 2048
#define NEXP 64
#define KC   64        // k-chunk
#define MT   16        // tokens per block
#define STR  68        // padded LDS stride (floats)

// workspace layout (floats): [0..63] f counts, [64..127] P sums, [128] sum lse^2
__global__ void zero_acc(float* acc) {
    int t = threadIdx.x;
    if (t < 129) acc[t] = 0.0f;
}

__global__ __launch_bounds__(256) void gate_main(
    const float* __restrict__ x, const float* __restrict__ W,
    const float* __restrict__ bias, float* __restrict__ out,
    float* __restrict__ acc_g)
{
    __shared__ __align__(16) float xs[MT * STR];    // 16 tokens x 64 k
    __shared__ __align__(16) float wsm[KC * STR];   // 64 k x 64 experts
    __shared__ int   f_loc[NEXP];
    __shared__ float p_loc[NEXP];
    __shared__ float z_loc;

    const int tid  = threadIdx.x;
    const int tok0 = blockIdx.x * MT;
    const int tx   = tid & 15;        // expert group: experts 4*tx..4*tx+3
    const int tg   = tid >> 4;        // token within block: 0..15
    const int e0   = tx * 4;

    if (tid < NEXP) { f_loc[tid] = 0; p_loc[tid] = 0.0f; }
    if (tid == 0) z_loc = 0.0f;

    float acc[4] = {0.f, 0.f, 0.f, 0.f};
    float bb[4];
    *(float4*)bb = *(const float4*)&bias[e0];

    // staging addresses: each thread owns 1 float4 of the x-chunk (1024 floats)
    // and 4 float4s of the W-chunk (4096 floats), lane-consecutive per instr.
    const float* xg = x + (size_t)(tok0 + tg) * DDIM + tx * 4;
    const float* wg = W + (size_t)(tid >> 4) * NEXP + (tid & 15) * 4; // + u*16 rows

    float4 px;
    float4 pw[4];
    px = *(const float4*)xg;
    #pragma unroll
    for (int u = 0; u < 4; ++u)
        pw[u] = *(const float4*)(wg + (size_t)u * 16 * NEXP);

    const int NCH = DDIM / KC;  // 32
    for (int c = 0; c < NCH; ++c) {
        __syncthreads();  // previous chunk's reads done
        *(float4*)&xs[tg * STR + tx * 4] = px;
        #pragma unroll
        for (int u = 0; u < 4; ++u)
            *(float4*)&wsm[((tid >> 4) + u * 16) * STR + (tid & 15) * 4] = pw[u];
        __syncthreads();
        if (c + 1 < NCH) {
            const float* xg2 = xg + (c + 1) * KC;
            const float* wg2 = wg + (size_t)(c + 1) * KC * NEXP;
            px = *(const float4*)xg2;
            #pragma unroll
            for (int u = 0; u < 4; ++u)
                pw[u] = *(const float4*)(wg2 + (size_t)u * 16 * NEXP);
        }
        #pragma unroll
        for (int kk = 0; kk < KC / 4; ++kk) {
            float xr[4];
            *(float4*)xr = *(const float4*)&xs[tg * STR + kk * 4];
            float wr[4][4];
            #pragma unroll
            for (int r = 0; r < 4; ++r)
                *(float4*)wr[r] = *(const float4*)&wsm[(kk * 4 + r) * STR + e0];
            #pragma unroll
            for (int r = 0; r < 4; ++r)   // k ascending: bitwise-identical to r1
                #pragma unroll
                for (int j = 0; j < 4; ++j)
                    acc[j] = fmaf(xr[r], wr[r][j], acc[j]);
        }
    }

    // ---- epilogue: 16 lanes per token (lanes sharing tg) ----
    float l[4];
    #pragma unroll
    for (int j = 0; j < 4; ++j) l[j] = acc[j] + bb[j];

    // local top-2 (stable: ascending e, strict >)
    float v1 = l[0], v2 = -INFINITY;
    int   i1 = e0,   i2 = 0x7fffffff;
    #pragma unroll
    for (int j = 1; j < 4; ++j) {
        float v = l[j]; int e = e0 + j;
        if (v > v1)      { v2 = v1; i2 = i1; v1 = v; i1 = e; }
        else if (v > v2) { v2 = v;  i2 = e; }
    }
    // merge across the 16 lanes of this token (comparator: value desc, idx asc)
    #pragma unroll
    for (int off = 1; off < 16; off <<= 1) {
        float o1 = __shfl_xor(v1, off, 16); int oi1 = __shfl_xor(i1, off, 16);
        float o2 = __shfl_xor(v2, off, 16); int oi2 = __shfl_xor(i2, off, 16);
        if (o1 > v1 || (o1 == v1 && oi1 < i1)) {
            float c = v1; int ci = i1;
            v1 = o1; i1 = oi1;
            if (c > o2 || (c == o2 && ci < oi2)) { v2 = c;  i2 = ci;  }
            else                                 { v2 = o2; i2 = oi2; }
        } else {
            if (o1 > v2 || (o1 == v2 && oi1 < i2)) { v2 = o1; i2 = oi1; }
        }
    }
    const float mx = v1;  // token max

    float s[4], dsum = 0.0f;
    #pragma unroll
    for (int j = 0; j < 4; ++j) { s[j] = __expf(l[j] - mx); dsum += s[j]; }
    #pragma unroll
    for (int off = 1; off < 16; off <<= 1) dsum += __shfl_xor(dsum, off, 16);
    const float inv = 1.0f / dsum;

    float p[4], zsum = 0.0f;
    #pragma unroll
    for (int j = 0; j < 4; ++j) { p[j] = s[j] * inv; zsum += __expf(p[j]); }
    #pragma unroll
    for (int off = 1; off < 16; off <<= 1) zsum += __shfl_xor(zsum, off, 16);

    // outputs (one lane per token)
    if (tx == 0) {
        const int gt = tok0 + tg;
        const float s2 = __expf(v2 - mx);       // s1 == 1
        const float ci = 1.0f / (1.0f + s2);
        out[2 * gt]     = (float)i1;
        out[2 * gt + 1] = (float)i2;
        out[2 * NTOK + 2 * gt]     = ci;
        out[2 * NTOK + 2 * gt + 1] = s2 * ci;
        atomicAdd(&f_loc[i1], 1);
    }

    // z-loss: one contribution per token, wave-reduce then LDS
    {
        float lse = __logf(zsum);
        float l2  = (tx == 0) ? lse * lse : 0.0f;
        #pragma unroll
        for (int off = 1; off < 64; off <<= 1) l2 += __shfl_xor(l2, off);
        if ((tid & 63) == 0) atomicAdd(&z_loc, l2);
    }

    // P column sums: fold the 4 token-groups within each wave, then LDS
    #pragma unroll
    for (int j = 0; j < 4; ++j) {
        p[j] += __shfl_xor(p[j], 16);
        p[j] += __shfl_xor(p[j], 32);
    }
    if ((tid & 63) < 16) {
        #pragma unroll
        for (int j = 0; j < 4; ++j) atomicAdd(&p_loc[e0 + j], p[j]);
    }

    __syncthreads();
    if (tid < NEXP) {
        atomicAdd(&acc_g[64 + tid], p_loc[tid]);
        if (f_loc[tid]) atomicAdd(&acc_g[tid], (float)f_loc[tid]);
    }
    if (tid == 0) atomicAdd(&acc_g[128], z_loc);
}

__global__ void gate_finalize(const float* __restrict__ acc, float* __restrict__ out) {
    int e = threadIdx.x;  // 64 threads
    float v = acc[e] * acc[64 + e];
    #pragma unroll
    for (int off = 32; off > 0; off >>= 1) v += __shfl_down(v, off);
    if (e == 0) {
        const float NT = (float)NTOK;
        out[2 * NTOK * 2]     = 0.01f * (v / (float)NEXP) / (NT * NT);
        out[2 * NTOK * 2 + 1] = 0.1f * acc[128] / NT;
    }
}

extern "C" void kernel_launch(void* const* d_in, const int* in_sizes, int n_in,
                              void* d_out, int out_size, void* d_ws, size_t ws_size,
                              hipStream_t stream) {
    const float* x    = (const float*)d_in[0];
    const float* W    = (const float*)d_in[1];
    const float* bias = (const float*)d_in[2];
    float* out = (float*)d_out;
    float* acc = (float*)d_ws;

    zero_acc<<<1, 256, 0, stream>>>(acc);
    gate_main<<<NTOK / MT, 256, 0, stream>>>(x, W, bias, out, acc);
    gate_finalize<<<1, 64, 0, stream>>>(acc, out);
}

// Round 3
// 103.381 us; speedup vs baseline: 3.4348x; 3.4348x over previous
//
#include <hip/hip_runtime.h>
#include <math.h>

#define NTOK 16384
#define DDIM 2048
#define NEXP 64
#define MT   64                  // tokens per stage-1 block
#define KSPLIT 4
#define KRANGE (DDIM / KSPLIT)   // 512
#define KC   32                  // k per LDS chunk
#define NCH  (KRANGE / KC)       // 16
#define XSTR 36                  // padded x-tile stride (floats)

// ws layout (floats): [0..63] f counts, [64..127] P sums, [128] sum lse^2,
// [256 ...] partial logits: [KSPLIT][NTOK][NEXP]
#define PART_OFF 256

__global__ void zero_acc(float* acc) {
    int t = threadIdx.x;
    if (t < 129) acc[t] = 0.0f;
}

__global__ __launch_bounds__(256) void gemm_part(
    const float* __restrict__ x, const float* __restrict__ W,
    float* __restrict__ pws)
{
    __shared__ __align__(16) float xs[MT * XSTR];    // 64 tok x 32 k (padded)
    __shared__ __align__(16) float wsm[KC * NEXP];   // 32 k x 64 experts

    const int tid  = threadIdx.x;
    const int tb   = blockIdx.x & 255;   // token block
    const int s    = blockIdx.x >> 8;    // k-split 0..3
    const int tok0 = tb * MT;
    const int kb   = s * KRANGE;

    const int tx = tid & 15;             // experts 4tx..4tx+3
    const int ty = tid >> 4;             // tokens 4ty..4ty+3

    // staging: x chunk 64x32 floats, 8 floats/thread (2 float4, coalesced)
    const int xr = tid >> 2;             // 0..63
    const int xc = (tid & 3) * 4;        // +16 for second float4
    // W chunk 32x64 floats, 8 floats/thread (2 float4, coalesced)
    const int wr = tid >> 3;             // 0..31
    const int wc = (tid & 7) * 4;        // +32 for second float4

    const float* xg = x + (size_t)(tok0 + xr) * DDIM + kb + xc;
    const float* wg = W + (size_t)(kb + wr) * NEXP + wc;

    float4 px0 = *(const float4*)xg;
    float4 px1 = *(const float4*)(xg + 16);
    float4 pw0 = *(const float4*)wg;
    float4 pw1 = *(const float4*)(wg + 32);

    float acc[4][4];
    #pragma unroll
    for (int t = 0; t < 4; ++t)
        #pragma unroll
        for (int j = 0; j < 4; ++j) acc[t][j] = 0.0f;

    for (int c = 0; c < NCH; ++c) {
        __syncthreads();   // previous chunk's LDS reads done
        *(float4*)&xs[xr * XSTR + xc]       = px0;
        *(float4*)&xs[xr * XSTR + xc + 16]  = px1;
        *(float4*)&wsm[wr * NEXP + wc]      = pw0;
        *(float4*)&wsm[wr * NEXP + wc + 32] = pw1;
        __syncthreads();
        if (c + 1 < NCH) {
            const float* xg2 = xg + (c + 1) * KC;
            const float* wg2 = wg + (size_t)(c + 1) * KC * NEXP;
            px0 = *(const float4*)xg2;
            px1 = *(const float4*)(xg2 + 16);
            pw0 = *(const float4*)wg2;
            pw1 = *(const float4*)(wg2 + 32);
        }
        #pragma unroll
        for (int kk = 0; kk < KC / 4; ++kk) {
            float xv[4][4], wv[4][4];
            #pragma unroll
            for (int t = 0; t < 4; ++t)
                *(float4*)xv[t] = *(const float4*)&xs[(ty * 4 + t) * XSTR + kk * 4];
            #pragma unroll
            for (int r = 0; r < 4; ++r)
                *(float4*)wv[r] = *(const float4*)&wsm[(kk * 4 + r) * NEXP + tx * 4];
            #pragma unroll
            for (int r = 0; r < 4; ++r)       // k ascending: deterministic order
                #pragma unroll
                for (int t = 0; t < 4; ++t)
                    #pragma unroll
                    for (int j = 0; j < 4; ++j)
                        acc[t][j] = fmaf(xv[t][r], wv[r][j], acc[t][j]);
        }
    }

    // store partial logits: pws[s][tok][e], coalesced float4 per row
    float* pb = pws + ((size_t)s * NTOK + tok0) * NEXP;
    #pragma unroll
    for (int t = 0; t < 4; ++t)
        *(float4*)&pb[(size_t)(ty * 4 + t) * NEXP + tx * 4] = *(float4*)acc[t];
}

__global__ __launch_bounds__(256) void epilogue(
    const float* __restrict__ pws, const float* __restrict__ bias,
    float* __restrict__ out, float* __restrict__ acc_g)
{
    __shared__ int   f_loc[NEXP];
    __shared__ float p_loc[NEXP];
    __shared__ float z_loc;

    const int tid = threadIdx.x;
    const int tx  = tid & 15;         // expert group: 4tx..4tx+3
    const int tg  = tid >> 4;         // token within block 0..15
    const int e0  = tx * 4;
    const int gt  = blockIdx.x * 16 + tg;

    if (tid < NEXP) { f_loc[tid] = 0; p_loc[tid] = 0.0f; }
    if (tid == 0) z_loc = 0.0f;
    __syncthreads();

    // sum 4 partials in fixed ascending-s order, then + bias
    float l[4];
    {
        const size_t ro = (size_t)gt * NEXP + e0;
        float4 p0 = *(const float4*)&pws[ro];
        float4 p1 = *(const float4*)&pws[(size_t)1 * NTOK * NEXP + ro];
        float4 p2 = *(const float4*)&pws[(size_t)2 * NTOK * NEXP + ro];
        float4 p3 = *(const float4*)&pws[(size_t)3 * NTOK * NEXP + ro];
        float bb[4];
        *(float4*)bb = *(const float4*)&bias[e0];
        l[0] = ((p0.x + p1.x) + p2.x) + p3.x + bb[0];
        l[1] = ((p0.y + p1.y) + p2.y) + p3.y + bb[1];
        l[2] = ((p0.z + p1.z) + p2.z) + p3.z + bb[2];
        l[3] = ((p0.w + p1.w) + p2.w) + p3.w + bb[3];
    }

    // local top-2 (stable: ascending e, strict >)
    float v1 = l[0], v2 = -INFINITY;
    int   i1 = e0,   i2 = 0x7fffffff;
    #pragma unroll
    for (int j = 1; j < 4; ++j) {
        float v = l[j]; int e = e0 + j;
        if (v > v1)      { v2 = v1; i2 = i1; v1 = v; i1 = e; }
        else if (v > v2) { v2 = v;  i2 = e; }
    }
    // merge across the 16 lanes of this token (value desc, idx asc)
    #pragma unroll
    for (int off = 1; off < 16; off <<= 1) {
        float o1 = __shfl_xor(v1, off, 16); int oi1 = __shfl_xor(i1, off, 16);
        float o2 = __shfl_xor(v2, off, 16); int oi2 = __shfl_xor(i2, off, 16);
        if (o1 > v1 || (o1 == v1 && oi1 < i1)) {
            float c = v1; int ci = i1;
            v1 = o1; i1 = oi1;
            if (c > o2 || (c == o2 && ci < oi2)) { v2 = c;  i2 = ci;  }
            else                                 { v2 = o2; i2 = oi2; }
        } else {
            if (o1 > v2 || (o1 == v2 && oi1 < i2)) { v2 = o1; i2 = oi1; }
        }
    }
    const float mx = v1;

    float sden[4], dsum = 0.0f;
    #pragma unroll
    for (int j = 0; j < 4; ++j) { sden[j] = __expf(l[j] - mx); dsum += sden[j]; }
    #pragma unroll
    for (int off = 1; off < 16; off <<= 1) dsum += __shfl_xor(dsum, off, 16);
    const float inv = 1.0f / dsum;

    float p[4], zsum = 0.0f;
    #pragma unroll
    for (int j = 0; j < 4; ++j) { p[j] = sden[j] * inv; zsum += __expf(p[j]); }
    #pragma unroll
    for (int off = 1; off < 16; off <<= 1) zsum += __shfl_xor(zsum, off, 16);

    if (tx == 0) {
        const float s2 = __expf(v2 - mx);      // s1 == 1
        const float ci = 1.0f / (1.0f + s2);
        out[2 * gt]     = (float)i1;
        out[2 * gt + 1] = (float)i2;
        out[2 * NTOK + 2 * gt]     = ci;
        out[2 * NTOK + 2 * gt + 1] = s2 * ci;
        atomicAdd(&f_loc[i1], 1);
    }

    {
        float lse = __logf(zsum);
        float l2  = (tx == 0) ? lse * lse : 0.0f;
        #pragma unroll
        for (int off = 1; off < 64; off <<= 1) l2 += __shfl_xor(l2, off);
        if ((tid & 63) == 0) atomicAdd(&z_loc, l2);
    }

    #pragma unroll
    for (int j = 0; j < 4; ++j) {
        p[j] += __shfl_xor(p[j], 16);
        p[j] += __shfl_xor(p[j], 32);
    }
    if ((tid & 63) < 16) {
        #pragma unroll
        for (int j = 0; j < 4; ++j) atomicAdd(&p_loc[e0 + j], p[j]);
    }

    __syncthreads();
    if (tid < NEXP) {
        atomicAdd(&acc_g[64 + tid], p_loc[tid]);
        if (f_loc[tid]) atomicAdd(&acc_g[tid], (float)f_loc[tid]);
    }
    if (tid == 0) atomicAdd(&acc_g[128], z_loc);
}

__global__ void gate_finalize(const float* __restrict__ acc, float* __restrict__ out) {
    int e = threadIdx.x;  // 64 threads
    float v = acc[e] * acc[64 + e];
    #pragma unroll
    for (int off = 32; off > 0; off >>= 1) v += __shfl_down(v, off);
    if (e == 0) {
        const float NT = (float)NTOK;
        out[2 * NTOK * 2]     = 0.01f * (v / (float)NEXP) / (NT * NT);
        out[2 * NTOK * 2 + 1] = 0.1f * acc[128] / NT;
    }
}

extern "C" void kernel_launch(void* const* d_in, const int* in_sizes, int n_in,
                              void* d_out, int out_size, void* d_ws, size_t ws_size,
                              hipStream_t stream) {
    const float* x    = (const float*)d_in[0];
    const float* W    = (const float*)d_in[1];
    const float* bias = (const float*)d_in[2];
    float* out = (float*)d_out;
    float* acc = (float*)d_ws;
    float* pws = acc + PART_OFF;

    zero_acc<<<1, 256, 0, stream>>>(acc);
    gemm_part<<<KSPLIT * (NTOK / MT), 256, 0, stream>>>(x, W, pws);
    epilogue<<<NTOK / 16, 256, 0, stream>>>(pws, bias, out, acc);
    gate_finalize<<<1, 64, 0, stream>>>(acc, out);
}